// Round 9
// baseline (428.578 us; speedup 1.0000x reference)
//
#include <hip/hip_runtime.h>

constexpr int B_ = 16, L_ = 2048, C_ = 256, K_ = 64, INNER_ = 4096;
constexpr int NCH = 32;          // L-chunks (RPB=64)
constexpr int RPB = 64;          // rows per k_em block
#define EPSF 1e-6f

typedef __attribute__((ext_vector_type(8)))  short bf16x8;
typedef __attribute__((ext_vector_type(4)))  float f32x4;
typedef __attribute__((ext_vector_type(16))) float f32x16;
typedef _Float16 f16;
typedef __attribute__((ext_vector_type(8))) _Float16 f16x8;
typedef __attribute__((ext_vector_type(4))) _Float16 f16x4;

__device__ __forceinline__ unsigned short f2bf(float f) {
  union { float f; unsigned u; } v; v.f = f;
  unsigned r = v.u + 0x7fffu + ((v.u >> 16) & 1u);   // RNE
  return (unsigned short)(r >> 16);
}

__device__ __forceinline__ void gload16(const void* src, void* lds) {
  __builtin_amdgcn_global_load_lds(
      (const __attribute__((address_space(1))) unsigned*)src,
      (__attribute__((address_space(3))) unsigned*)lds, 16, 0, 0);
}

// ---------------------------------------------------------------- k_pre
// w1fr: bn-scaled w1 in GEMM1 A-frag order:
//   f = ic*16384 + itile*8192 + ks*512 + l5*256 + l31*8 + j
//   (j:0-2, l31:3-7, l5:8, ks:9-12, itile:13, ic:14-19)
// w2fr: w2 in GEMM2 A-frag order with sigma k-permutation matching GEMM1's
//   D-register layout: f = g*4096 + l5*2048 + ot*256 + l31*8 + j,
//   holding w2[ot*32+l31][g*16 + 4*l5 + 8*(j>>2) + (j&3)].
__global__ __launch_bounds__(256) void k_pre(
    const float* __restrict__ w1, const float* __restrict__ w2,
    const float* __restrict__ gamma, const float* __restrict__ beta,
    const float* __restrict__ bmean, const float* __restrict__ bvar,
    const float* __restrict__ b1, const float* __restrict__ mu0,
    unsigned short* __restrict__ w1fr, unsigned short* __restrict__ w2fr,
    f16* __restrict__ bnshH, f16* __restrict__ muF)
{
  int i = blockIdx.x * 256 + threadIdx.x;     // covers 1048576
  if (i < INNER_ * C_) {
    int j = i & 7, l31 = (i >> 3) & 31;
    { // w1fr (FIXED decomposition: l5 bit 8, ks bits 9-12, itile bit 13, ic 14+)
      int l5 = (i >> 8) & 1, ks = (i >> 9) & 15, itile = (i >> 13) & 1, ic = i >> 14;
      int r1 = ic * 64 + itile * 32 + l31;          // 0..4095
      int c1 = ks * 16 + l5 * 8 + j;                // 0..255
      float sc = gamma[r1] * rsqrtf(bvar[r1] + 1e-5f);
      w1fr[i] = f2bf(w1[(size_t)r1 * C_ + c1] * sc);
    }
    { // w2fr: ot bits 8-10, l5 bit 11, g bits 12+
      int ot = (i >> 8) & 7, l5 = (i >> 11) & 1, g = i >> 12;
      int o = ot * 32 + l31;
      int ii = g * 16 + 4 * l5 + 8 * (j >> 2) + (j & 3);
      w2fr[i] = f2bf(w2[(size_t)o * INNER_ + ii]);
    }
  }
  if (i < B_ * K_ * C_) muF[i] = (f16)mu0[i & (K_ * C_ - 1)];
  if (i < INNER_) {
    float sc = gamma[i] * rsqrtf(bvar[i] + 1e-5f);
    bnshH[i] = (f16)fmaf(b1[i] - bmean[i], sc, beta[i]);
  }
}

// ---------------------------------------------------------------- k_xT
__global__ __launch_bounds__(256) void k_xT(const float* __restrict__ x,
                                            f16* __restrict__ xf, f16* __restrict__ xTf)
{
  __shared__ float ts[64][65];
  int l0 = blockIdx.x * 64, c0 = blockIdx.y * 64, b = blockIdx.z;
  int t = threadIdx.x;
  for (int p = 0; p < 16; ++p) {
    int e = t + p * 256, i = e >> 6, j = e & 63;
    float vv = x[((size_t)b * L_ + l0 + i) * C_ + c0 + j];
    ts[i][j] = vv;
    xf[((size_t)b * L_ + l0 + i) * C_ + c0 + j] = (f16)vv;
  }
  __syncthreads();
  for (int p = 0; p < 16; ++p) {
    int e = t + p * 256, i = e >> 6, j = e & 63;
    xTf[((size_t)b * C_ + c0 + i) * L_ + l0 + j] = (f16)ts[j][i];
  }
}

// ---------------------------------------------------------------- k_em (r7, unchanged)
template<bool DO_MU, bool WRITE_Z>
__global__ __launch_bounds__(256, 2) void k_em(
    const f16* __restrict__ xf, const f16* __restrict__ xTf,
    const f16* __restrict__ muF, f16* __restrict__ zout,
    float* __restrict__ cp, f16* __restrict__ part)
{
  __shared__ f16 mu_s[K_ * C_];
  __shared__ f16 zT_s[K_ * RPB];
  __shared__ f16 xtile[C_ * RPB];
  __shared__ float cpart[4][K_];

  int t = threadIdx.x, b = blockIdx.y, chn = blockIdx.x, l0 = chn * RPB;
  int w = t >> 6, lane = t & 63, l15 = lane & 15, g = lane >> 4;

#pragma unroll
  for (int q = 0; q < 8; ++q) {
    int s = q * 256 + t, k = s >> 5, sl = s & 31;
    gload16(muF + (size_t)b * (K_ * C_) + k * C_ + ((sl ^ (k & 15)) << 3), mu_s + s * 8);
  }
  __builtin_amdgcn_sched_barrier(0);
  f16x8 xfr[8];
  const f16* xr = xf + ((size_t)b * L_ + l0 + w * 16 + l15) * C_ + g * 8;
#pragma unroll
  for (int ck = 0; ck < 8; ++ck) xfr[ck] = *(const f16x8*)(xr + ck * 32);
  __builtin_amdgcn_sched_barrier(0);
  if (DO_MU) {
#pragma unroll
    for (int q = 0; q < 8; ++q) {
      int s = q * 256 + t, c = s >> 3, sl = s & 7;
      gload16(xTf + (size_t)(b * C_ + c) * L_ + l0 + ((sl ^ (c & 7)) << 3), xtile + s * 8);
    }
    __builtin_amdgcn_sched_barrier(0);
    asm volatile("s_waitcnt vmcnt(8)" ::: "memory");
  } else {
    asm volatile("s_waitcnt vmcnt(0)" ::: "memory");
  }
  __builtin_amdgcn_s_barrier();
  __builtin_amdgcn_sched_barrier(0);

  f32x4 acc[4];
#pragma unroll
  for (int mt = 0; mt < 4; ++mt)
#pragma unroll
    for (int j = 0; j < 4; ++j) acc[mt][j] = 0.f;
#pragma unroll
  for (int ck = 0; ck < 8; ++ck) {
#pragma unroll
    for (int mt = 0; mt < 4; ++mt) {
      f16x8 a = *(const f16x8*)(mu_s + (mt * 16 + l15) * C_ + (((ck * 4 + g) ^ l15) << 3));
      acc[mt] = __builtin_amdgcn_mfma_f32_16x16x32_f16(a, xfr[ck], acc[mt], 0, 0, 0);
    }
  }

  float z[4][4];
  {
    float mx = acc[0][0];
#pragma unroll
    for (int mt = 0; mt < 4; ++mt)
#pragma unroll
      for (int jj = 0; jj < 4; ++jj) mx = fmaxf(mx, acc[mt][jj]);
    mx = fmaxf(mx, __shfl_xor(mx, 16, 64));
    mx = fmaxf(mx, __shfl_xor(mx, 32, 64));
    float sm = 0.f;
#pragma unroll
    for (int mt = 0; mt < 4; ++mt)
#pragma unroll
      for (int jj = 0; jj < 4; ++jj) {
        float e = __expf(acc[mt][jj] - mx);
        z[mt][jj] = e; sm += e;
      }
    sm += __shfl_xor(sm, 16, 64);
    sm += __shfl_xor(sm, 32, 64);
    float inv = 1.f / sm;
#pragma unroll
    for (int mt = 0; mt < 4; ++mt)
#pragma unroll
      for (int jj = 0; jj < 4; ++jj) z[mt][jj] *= inv;
  }

#pragma unroll
  for (int mt = 0; mt < 4; ++mt)
#pragma unroll
    for (int jj = 0; jj < 4; ++jj) {
      float v = z[mt][jj];
      v += __shfl_xor(v, 1, 64); v += __shfl_xor(v, 2, 64);
      v += __shfl_xor(v, 4, 64); v += __shfl_xor(v, 8, 64);
      if (l15 == 0) cpart[w][mt * 16 + g * 4 + jj] = v;
    }

#pragma unroll
  for (int mt = 0; mt < 4; ++mt)
#pragma unroll
    for (int jj = 0; jj < 4; ++jj) {
      int k = mt * 16 + g * 4 + jj;
      int tl = w * 16 + l15;
      f16 h = (f16)z[mt][jj];
      if (DO_MU)   zT_s[k * RPB + (((tl >> 3) ^ (k & 7)) << 3) + (tl & 7)] = h;
      if (WRITE_Z) zout[((size_t)b * L_ + l0 + tl) * K_ + k] = h;
    }
  __syncthreads();

  if (t < K_) {
    float s = 0.f;
#pragma unroll
    for (int q = 0; q < 4; ++q) s += cpart[q][t];
    cp[(size_t)chn * (B_ * K_) + b * K_ + t] = s;
  }

  if (DO_MU) {
    f32x4 a3[4][4];
#pragma unroll
    for (int mt = 0; mt < 4; ++mt)
#pragma unroll
      for (int nt = 0; nt < 4; ++nt)
#pragma unroll
        for (int j = 0; j < 4; ++j) a3[mt][nt][j] = 0.f;
    int cb = w * 64;
#pragma unroll
    for (int ks = 0; ks < 2; ++ks) {
      f16x8 az[4], bx[4];
#pragma unroll
      for (int mt = 0; mt < 4; ++mt)
        az[mt] = *(const f16x8*)(zT_s + (mt * 16 + l15) * RPB + (((ks * 4 + g) ^ (l15 & 7)) << 3));
#pragma unroll
      for (int nt = 0; nt < 4; ++nt) {
        int c = cb + nt * 16 + l15;
        bx[nt] = *(const f16x8*)(xtile + c * RPB + (((ks * 4 + g) ^ (c & 7)) << 3));
      }
#pragma unroll
      for (int mt = 0; mt < 4; ++mt)
#pragma unroll
        for (int nt = 0; nt < 4; ++nt)
          a3[mt][nt] = __builtin_amdgcn_mfma_f32_16x16x32_f16(az[mt], bx[nt], a3[mt][nt], 0, 0, 0);
    }
    f16* pp = part + (((size_t)chn * B_ + b) * K_) * C_;
#pragma unroll
    for (int mt = 0; mt < 4; ++mt)
#pragma unroll
      for (int nt = 0; nt < 4; ++nt)
#pragma unroll
        for (int jj = 0; jj < 4; ++jj)
          pp[(size_t)(mt * 16 + g * 4 + jj) * C_ + cb + nt * 16 + l15] = (f16)a3[mt][nt][jj];
  }
}

// ---------------------------------------------------------------- k_mufin
template<bool LAST>
__global__ __launch_bounds__(256) void k_mufin(
    const f16* __restrict__ part, const float* __restrict__ cp,
    f16* __restrict__ muF, f16* __restrict__ muT,
    float* __restrict__ zsA, float* __restrict__ outmu)
{
  int b = blockIdx.x >> 4, kg = blockIdx.x & 15, t = threadIdx.x;
  int kr = t >> 6, c4 = t & 63, k = kg * 4 + kr;
  float a0 = 0.f, a1 = 0.f, a2 = 0.f, a3 = 0.f;
#pragma unroll
  for (int chn = 0; chn < NCH; ++chn) {
    f16x4 p = *(const f16x4*)(part + (((size_t)chn * B_ + b) * K_ + k) * C_ + c4 * 4);
    a0 += (float)p[0]; a1 += (float)p[1]; a2 += (float)p[2]; a3 += (float)p[3];
  }
  float zs = 0.f;
#pragma unroll
  for (int chn = 0; chn < NCH; ++chn) zs += cp[(size_t)chn * (B_ * K_) + b * K_ + k];
  float sc = 1.f / (EPSF + zs);
  a0 *= sc; a1 *= sc; a2 *= sc; a3 *= sc;
  float ssq = a0 * a0 + a1 * a1 + a2 * a2 + a3 * a3;
#pragma unroll
  for (int off = 32; off >= 1; off >>= 1) ssq += __shfl_xor(ssq, off, 64);
  float inv = 1.f / (EPSF + sqrtf(ssq));
  a0 *= inv; a1 *= inv; a2 *= inv; a3 *= inv;
  size_t base = (size_t)(b * K_ + k) * C_ + c4 * 4;
  f16x4 hm; hm[0] = (f16)a0; hm[1] = (f16)a1; hm[2] = (f16)a2; hm[3] = (f16)a3;
  *(f16x4*)(muF + base) = hm;
  if (c4 == 0) zsA[b * K_ + k] = zs;
  if (LAST) {
    *(float4*)(outmu + base) = make_float4(a0, a1, a2, a3);
    muT[((size_t)b * C_ + c4 * 4 + 0) * K_ + k] = hm[0];
    muT[((size_t)b * C_ + c4 * 4 + 1) * K_ + k] = hm[1];
    muT[((size_t)b * C_ + c4 * 4 + 2) * K_ + k] = hm[2];
    muT[((size_t)b * C_ + c4 * 4 + 3) * K_ + k] = hm[3];
  }
}

// ---------------------------------------------------------------- k_attn
__global__ __launch_bounds__(256) void k_attn(
    const f16* __restrict__ zB, const float* __restrict__ cpB, float* __restrict__ attn)
{
  __shared__ float zt[64][68];
  __shared__ float inv_s[K_];
  int b = blockIdx.y, l0 = blockIdx.x * 64, t = threadIdx.x;
  if (t < K_) {
    float zs = 0.f;
#pragma unroll
    for (int chn = 0; chn < NCH; ++chn) zs += cpB[(size_t)chn * (B_ * K_) + b * K_ + t];
    inv_s[t] = 1.f / (EPSF + zs);
  }
  for (int p = 0; p < 16; ++p) {
    int e = t + p * 256, lo = e >> 6, k = e & 63;
    zt[lo][k] = (float)zB[((size_t)b * L_ + l0 + lo) * K_ + k];
  }
  __syncthreads();
  int lo = t & 63, kb = t >> 6;
  for (int p = 0; p < 16; ++p) {
    int k = kb * 16 + p;
    attn[((size_t)b * K_ + k) * L_ + l0 + lo] = zt[lo][k] * inv_s[k];
  }
}

// ---------------------------------------------------------------- k_mlp
// Design D: 4 waves x 32 private toks; GEMM1 D-layout feeds GEMM2 B directly
// (sigma-permuted w2fr). 1 barrier + 1 iter-old vmcnt(0) per iter. 1 blk/CU.
constexpr int MUT_OFF  = 0;        // prologue 32KB
constexpr int ZS_OFF   = 32768;    // prologue 16KB
constexpr int RCS_OFF  = 49152;    // prologue 64KB (ends 114688)
constexpr int W1S_OFF  = 0;        // main 2x32KB
constexpr int W2S_OFF  = 65536;    // main 2x32KB
constexpr int BNS_OFF  = 131072;   // 8KB (persistent)
constexpr int ZINV_OFF = 139264;   // 256B
constexpr int POOL_SZ  = 139520;

__global__ __launch_bounds__(256, 1) void k_mlp(
    const f16* __restrict__ zA,                  // [BL][64]
    const f16* __restrict__ muT,                 // [B][C][K]
    const float* __restrict__ zsA,               // [B][K]
    const unsigned short* __restrict__ w1fr,     // frag-ordered, bn-scaled
    const unsigned short* __restrict__ w2fr,     // frag-ordered, sigma-permuted
    const f16* __restrict__ bnshH, const float* __restrict__ b2,
    float* __restrict__ outr)                    // [BL][256] f32
{
  __shared__ __align__(16) char pool[POOL_SZ];
  f16* muT_s          = (f16*)(pool + MUT_OFF);
  f16* z_s            = (f16*)(pool + ZS_OFF);
  unsigned short* rcs = (unsigned short*)(pool + RCS_OFF);
  unsigned short* w1s = (unsigned short*)(pool + W1S_OFF);
  unsigned short* w2s = (unsigned short*)(pool + W2S_OFF);
  f16* bns_s          = (f16*)(pool + BNS_OFF);
  float* zinv_s       = (float*)(pool + ZINV_OFF);

  int t = threadIdx.x, w = t >> 6, lane = t & 63, l31 = lane & 31, l5 = lane >> 5;
  int rb = blockIdx.x * 128, b = rb >> 11, l0 = rb & 2047;

  // ---- prologue staging: zinv, muT (32KB), z (16KB), bns (8KB)
  if (t < K_) zinv_s[t] = 1.f / (EPSF + zsA[b * K_ + t]);
#pragma unroll
  for (int q = 0; q < 8; ++q) {
    int s = q * 256 + t, c = s >> 3, sl = s & 7;
    gload16(muT + ((size_t)b * C_ + c) * K_ + ((sl ^ (c & 7)) << 3), muT_s + s * 8);
  }
#pragma unroll
  for (int q = 0; q < 4; ++q) {
    int s = q * 256 + t, tok = s >> 3, sl = s & 7;
    gload16(zA + ((size_t)b * L_ + l0 + tok) * K_ + ((sl ^ (tok & 7)) << 3), z_s + s * 8);
  }
#pragma unroll
  for (int q = 0; q < 2; ++q) {
    int s = q * 256 + t;
    gload16(bnshH + s * 8, bns_s + s * 8);
  }
  asm volatile("s_waitcnt vmcnt(0) lgkmcnt(0)" ::: "memory");
  __builtin_amdgcn_s_barrier();
  __builtin_amdgcn_sched_barrier(0);

  // ---- recon MFMA: wave w owns c-range w*64 (m 0..1), all 4 tok-tiles
  {
    f32x16 d[2][4];
#pragma unroll
    for (int m = 0; m < 2; ++m)
#pragma unroll
      for (int tt = 0; tt < 4; ++tt)
#pragma unroll
        for (int r = 0; r < 16; ++r) d[m][tt][r] = 0.f;
#pragma unroll
    for (int kk = 0; kk < 4; ++kk) {
      f16x8 bz[4];
#pragma unroll
      for (int tt = 0; tt < 4; ++tt) {
        int tok = tt * 32 + l31;
        f16x8 zr = *(const f16x8*)(z_s + tok * 64 + (((kk * 2 + l5) ^ (tok & 7)) << 3));
        f16x8 sc2;
#pragma unroll
        for (int e = 0; e < 8; ++e)
          sc2[e] = (f16)((float)zr[e] * zinv_s[kk * 16 + l5 * 8 + e]);
        bz[tt] = sc2;
      }
#pragma unroll
      for (int m = 0; m < 2; ++m) {
        int c = w * 64 + m * 32 + l31;
        f16x8 am = *(const f16x8*)(muT_s + c * 64 + (((kk * 2 + l5) ^ (c & 7)) << 3));
#pragma unroll
        for (int tt = 0; tt < 4; ++tt)
          d[m][tt] = __builtin_amdgcn_mfma_f32_32x32x16_f16(am, bz[tt], d[m][tt], 0, 0, 0);
      }
    }
    // scatter into rc B-frag layout (rcs disjoint from muT_s/z_s), packed b32
#pragma unroll
    for (int m = 0; m < 2; ++m)
#pragma unroll
      for (int tt = 0; tt < 4; ++tt)
#pragma unroll
        for (int rp = 0; rp < 8; ++rp) {
          int r0 = rp * 2;
          int c = w * 64 + m * 32 + (r0 & 3) + 8 * (r0 >> 2) + 4 * l5;
          int ks = c >> 4, l5p = (c >> 3) & 1, j = c & 7;
          unsigned u = (unsigned)f2bf(d[m][tt][r0]) | ((unsigned)f2bf(d[m][tt][r0 + 1]) << 16);
          *(unsigned*)(rcs + (((tt * 16 + ks) * 64) + l5p * 32 + l31) * 8 + j) = u;
        }
  }
  asm volatile("s_waitcnt lgkmcnt(0)" ::: "memory");
  __builtin_amdgcn_s_barrier();        // rcs complete (cross-wave)
  __builtin_amdgcn_sched_barrier(0);

  // persistent recon B-frags: wave's tok-tile = w
  bf16x8 rc[16];
#pragma unroll
  for (int ks = 0; ks < 16; ++ks)
    rc[ks] = *(const bf16x8*)(rcs + ((w * 16 + ks) * 64 + lane) * 8);
  asm volatile("s_waitcnt lgkmcnt(0)" ::: "memory");
  __builtin_amdgcn_s_barrier();        // rc in regs -> pool reusable
  __builtin_amdgcn_sched_barrier(0);

  f32x16 acc2[8];
#pragma unroll
  for (int ot = 0; ot < 8; ++ot)
#pragma unroll
    for (int r = 0; r < 16; ++r) acc2[ot][r] = 0.f;

#define STAGE(ic, buf)                                                    \
  {                                                                       \
    _Pragma("unroll")                                                     \
    for (int q = 0; q < 8; ++q) {                                         \
      int d2 = q * 256 + t;                                               \
      gload16(w1fr + (size_t)(ic) * 16384 + d2 * 8,                       \
              w1s + (size_t)(buf) * 16384 + d2 * 8);                      \
    }                                                                     \
    _Pragma("unroll")                                                     \
    for (int q = 0; q < 8; ++q) {                                         \
      int d2 = q * 256 + t;                                               \
      gload16(w2fr + (size_t)(ic) * 16384 + d2 * 8,                       \
              w2s + (size_t)(buf) * 16384 + d2 * 8);                      \
    }                                                                     \
  }

  STAGE(0, 0);
  const unsigned short* p1base = w1s + l5 * 256 + l31 * 8;
  const unsigned short* p2base = w2s + l5 * 2048 + l31 * 8;

  for (int ic = 0; ic < 64; ++ic) {
    int cur = ic & 1;
    asm volatile("s_waitcnt vmcnt(0)" ::: "memory");   // STAGE(ic): iter-old
    __builtin_amdgcn_s_barrier();
    __builtin_amdgcn_sched_barrier(0);
    if (ic < 63) STAGE(ic + 1, cur ^ 1);
    __builtin_amdgcn_sched_barrier(0);

#pragma unroll
    for (int itile = 0; itile < 2; ++itile) {
      // ---- GEMM1: h^T[i-tile][wave's 32 toks], K=256 via rc[16]
      f32x16 h0, h1;
#pragma unroll
      for (int r = 0; r < 16; ++r) { h0[r] = 0.f; h1[r] = 0.f; }
      const unsigned short* p1 = p1base + cur * 16384 + itile * 8192;
#pragma unroll
      for (int ks = 0; ks < 16; ++ks) {
        bf16x8 a1 = *(const bf16x8*)(p1 + ks * 512);
        if (ks & 1) h1 = __builtin_amdgcn_mfma_f32_32x32x16_bf16(a1, rc[ks], h1, 0, 0, 0);
        else        h0 = __builtin_amdgcn_mfma_f32_32x32x16_bf16(a1, rc[ks], h0, 0, 0, 0);
      }
#pragma unroll
      for (int r = 0; r < 16; ++r) h0[r] += h1[r];

      // ---- BN shift + ReLU + pack into GEMM2 B-frags (no LDS, no shuffle)
      f16x4 bnv[4];
#pragma unroll
      for (int q = 0; q < 4; ++q)
        bnv[q] = *(const f16x4*)(bns_s + ic * 64 + itile * 32 + 8 * q + 4 * l5);
      unsigned pk[8];
#pragma unroll
      for (int q = 0; q < 4; ++q) {
#pragma unroll
        for (int pr = 0; pr < 2; ++pr) {
          int r0 = q * 4 + pr * 2;
          float v0 = fmaxf(h0[r0]     + (float)bnv[q][pr * 2],     0.f);
          float v1 = fmaxf(h0[r0 + 1] + (float)bnv[q][pr * 2 + 1], 0.f);
          pk[q * 2 + pr] = (unsigned)f2bf(v0) | ((unsigned)f2bf(v1) << 16);
        }
      }
      union Uf { unsigned u[4]; bf16x8 v; };
      Uf bfr0, bfr1;
#pragma unroll
      for (int m = 0; m < 4; ++m) { bfr0.u[m] = pk[m]; bfr1.u[m] = pk[4 + m]; }

      // ---- GEMM2: all 8 o-tiles, k-steps g = ic*4 + itile*2 + {0,1}
      const unsigned short* p2 = p2base + cur * 16384;
#pragma unroll
      for (int s = 0; s < 2; ++s) {
        int gl = itile * 2 + s;
        bf16x8 bfv = s ? bfr1.v : bfr0.v;
#pragma unroll
        for (int ot = 0; ot < 8; ++ot) {
          bf16x8 a2 = *(const bf16x8*)(p2 + gl * 4096 + ot * 256);
          acc2[ot] = __builtin_amdgcn_mfma_f32_32x32x16_bf16(a2, bfv, acc2[ot], 0, 0, 0);
        }
      }
    }
  }
#undef STAGE

  // ---- epilogue: + b2, f32x4 stores (wave-private toks)
  int tok = rb + w * 32 + l31;
#pragma unroll
  for (int ot = 0; ot < 8; ++ot) {
#pragma unroll
    for (int q = 0; q < 4; ++q) {
      int o = ot * 32 + 8 * q + 4 * l5;
      float4 bias = *(const float4*)(b2 + o);
      f32x4 v;
      v[0] = acc2[ot][q * 4 + 0] + bias.x;
      v[1] = acc2[ot][q * 4 + 1] + bias.y;
      v[2] = acc2[ot][q * 4 + 2] + bias.z;
      v[3] = acc2[ot][q * 4 + 3] + bias.w;
      *(f32x4*)(outr + (size_t)tok * C_ + o) = v;
    }
  }
}

// ---------------------------------------------------------------- launch
extern "C" void kernel_launch(void* const* d_in, const int* in_sizes, int n_in,
                              void* d_out, int out_size, void* d_ws, size_t ws_size,
                              hipStream_t stream)
{
  const float* x     = (const float*)d_in[0];
  const float* mu0   = (const float*)d_in[2];
  const float* w1    = (const float*)d_in[3];
  const float* b1    = (const float*)d_in[4];
  const float* gamma = (const float*)d_in[5];
  const float* beta  = (const float*)d_in[6];
  const float* bmean = (const float*)d_in[7];
  const float* bvar  = (const float*)d_in[8];
  const float* w2    = (const float*)d_in[9];
  const float* b2    = (const float*)d_in[10];
  float* out = (float*)d_out;

  char* wsb = (char*)d_ws;
  f16* part = (f16*)(wsb + 0);                                  // 16,777,216 B
  f16* zB   = part;                                             // alias (dead after last mufin)
  f16* zA   = (f16*)(wsb + 16777216);                           // 4,194,304
  f16* xf   = (f16*)(wsb + 20971520);                           // 16,777,216
  f16* xTf  = (f16*)(wsb + 37748736);                           // 16,777,216
  unsigned short* w1fr = (unsigned short*)(wsb + 54525952);     // 2,097,152
  unsigned short* w2fr = (unsigned short*)(wsb + 56623104);     // 2,097,152
  f16*   muF   = (f16*)(wsb + 58720256);                        // 524,288
  f16*   muT   = (f16*)(wsb + 59244544);                        // 524,288
  f16*   bnshH = (f16*)(wsb + 59768832);                        // 8,192
  float* cpA   = (float*)(wsb + 59777024);                      // 131,072
  float* cpB   = (float*)(wsb + 59908096);                      // 131,072
  float* zsA   = (float*)(wsb + 60039168);                      // 4,096  (~60MB)

  k_pre<<<4096, 256, 0, stream>>>(w1, w2, gamma, beta, bmean, bvar, b1, mu0,
                                  w1fr, w2fr, bnshH, muF);
  k_xT<<<dim3(32, 4, 16), 256, 0, stream>>>(x, xf, xTf);

  for (int s = 0; s < 10; ++s) {
    if (s == 9) k_em<true, true ><<<dim3(NCH, 16), 256, 0, stream>>>(xf, xTf, muF, zA, cpA, part);
    else        k_em<true, false><<<dim3(NCH, 16), 256, 0, stream>>>(xf, xTf, muF, zA, cpA, part);
    if (s == 9) k_mufin<true ><<<256, 256, 0, stream>>>(part, cpA, muF, muT, zsA, out);
    else        k_mufin<false><<<256, 256, 0, stream>>>(part, cpA, muF, muT, zsA, out);
  }
  // new_z with final mu (no mu-update; zB overlays dead part buffer)
  k_em<false, true><<<dim3(NCH, 16), 256, 0, stream>>>(xf, xTf, muF, zB, cpB, part);
  k_attn<<<dim3(32, 16), 256, 0, stream>>>(zB, cpB, out + 262144);
  k_recon_dummy:;
  k_mlp<<<256, 256, 0, stream>>>(zA, muT, zsA, w1fr, w2fr, bnshH, b2, out + 2359296);
}

// Round 10
// 355.495 us; speedup vs baseline: 1.2056x; 1.2056x over previous
//
#include <hip/hip_runtime.h>

constexpr int B_ = 16, L_ = 2048, C_ = 256, K_ = 64, INNER_ = 4096;
constexpr int NCH = 32;          // L-chunks (RPB=64)
constexpr int RPB = 64;          // rows per k_em block
#define EPSF 1e-6f

typedef __attribute__((ext_vector_type(8)))  short bf16x8;
typedef __attribute__((ext_vector_type(4)))  float f32x4;
typedef __attribute__((ext_vector_type(16))) float f32x16;
typedef _Float16 f16;
typedef __attribute__((ext_vector_type(8))) _Float16 f16x8;
typedef __attribute__((ext_vector_type(4))) _Float16 f16x4;

__device__ __forceinline__ unsigned short f2bf(float f) {
  union { float f; unsigned u; } v; v.f = f;
  unsigned r = v.u + 0x7fffu + ((v.u >> 16) & 1u);   // RNE
  return (unsigned short)(r >> 16);
}

__device__ __forceinline__ void gload16(const void* src, void* lds) {
  __builtin_amdgcn_global_load_lds(
      (const __attribute__((address_space(1))) unsigned*)src,
      (__attribute__((address_space(3))) unsigned*)lds, 16, 0, 0);
}

// ---------------------------------------------------------------- k_pre
// w1fr: bn-scaled w1, GEMM1 A-frag order WITH sigma k-permutation:
//   f = ic*16384 + ih*8192 + ks*512 + l5*256 + l31*8 + j
//   holds w1[ic*64 + ih*32 + l31][ks*16 + 4*l5 + 8*(j>>2) + (j&3)] * bnscale
//   (sigma matches the 32x32 MFMA D-layout so recon/h D-regs ARE B-frags)
// w2fr: w2, GEMM2 A-frag order with same sigma:
//   f = g*4096 + l5*2048 + ot*256 + l31*8 + j
//   holds w2[ot*32 + l31][g*16 + 4*l5 + 8*(j>>2) + (j&3)]
__global__ __launch_bounds__(256) void k_pre(
    const float* __restrict__ w1, const float* __restrict__ w2,
    const float* __restrict__ gamma, const float* __restrict__ beta,
    const float* __restrict__ bmean, const float* __restrict__ bvar,
    const float* __restrict__ b1, const float* __restrict__ mu0,
    unsigned short* __restrict__ w1fr, unsigned short* __restrict__ w2fr,
    f16* __restrict__ bnshH, f16* __restrict__ muF)
{
  int i = blockIdx.x * 256 + threadIdx.x;     // covers 1048576
  if (i < INNER_ * C_) {
    int j = i & 7, l31 = (i >> 3) & 31;
    { // w1fr: l5 bit 8, ks bits 9-12, ih bit 13, ic bits 14+
      int l5 = (i >> 8) & 1, ks = (i >> 9) & 15, ih = (i >> 13) & 1, ic = i >> 14;
      int r1 = ic * 64 + ih * 32 + l31;             // 0..4095
      int c1 = ks * 16 + 4 * l5 + 8 * (j >> 2) + (j & 3);   // sigma
      float sc = gamma[r1] * rsqrtf(bvar[r1] + 1e-5f);
      w1fr[i] = f2bf(w1[(size_t)r1 * C_ + c1] * sc);
    }
    { // w2fr: ot bits 8-10, l5 bit 11, g bits 12+
      int ot = (i >> 8) & 7, l5 = (i >> 11) & 1, g = i >> 12;
      int o = ot * 32 + l31;
      int ii = g * 16 + 4 * l5 + 8 * (j >> 2) + (j & 3);
      w2fr[i] = f2bf(w2[(size_t)o * INNER_ + ii]);
    }
  }
  if (i < B_ * K_ * C_) muF[i] = (f16)mu0[i & (K_ * C_ - 1)];
  if (i < INNER_) {
    float sc = gamma[i] * rsqrtf(bvar[i] + 1e-5f);
    bnshH[i] = (f16)fmaf(b1[i] - bmean[i], sc, beta[i]);
  }
}

// ---------------------------------------------------------------- k_xT
__global__ __launch_bounds__(256) void k_xT(const float* __restrict__ x,
                                            f16* __restrict__ xf, f16* __restrict__ xTf)
{
  __shared__ float ts[64][65];
  int l0 = blockIdx.x * 64, c0 = blockIdx.y * 64, b = blockIdx.z;
  int t = threadIdx.x;
  for (int p = 0; p < 16; ++p) {
    int e = t + p * 256, i = e >> 6, j = e & 63;
    float vv = x[((size_t)b * L_ + l0 + i) * C_ + c0 + j];
    ts[i][j] = vv;
    xf[((size_t)b * L_ + l0 + i) * C_ + c0 + j] = (f16)vv;
  }
  __syncthreads();
  for (int p = 0; p < 16; ++p) {
    int e = t + p * 256, i = e >> 6, j = e & 63;
    xTf[((size_t)b * C_ + c0 + i) * L_ + l0 + j] = (f16)ts[j][i];
  }
}

// ---------------------------------------------------------------- k_em (r7, unchanged)
template<bool DO_MU, bool WRITE_Z>
__global__ __launch_bounds__(256, 2) void k_em(
    const f16* __restrict__ xf, const f16* __restrict__ xTf,
    const f16* __restrict__ muF, f16* __restrict__ zout,
    float* __restrict__ cp, f16* __restrict__ part)
{
  __shared__ f16 mu_s[K_ * C_];
  __shared__ f16 zT_s[K_ * RPB];
  __shared__ f16 xtile[C_ * RPB];
  __shared__ float cpart[4][K_];

  int t = threadIdx.x, b = blockIdx.y, chn = blockIdx.x, l0 = chn * RPB;
  int w = t >> 6, lane = t & 63, l15 = lane & 15, g = lane >> 4;

#pragma unroll
  for (int q = 0; q < 8; ++q) {
    int s = q * 256 + t, k = s >> 5, sl = s & 31;
    gload16(muF + (size_t)b * (K_ * C_) + k * C_ + ((sl ^ (k & 15)) << 3), mu_s + s * 8);
  }
  __builtin_amdgcn_sched_barrier(0);
  f16x8 xfr[8];
  const f16* xr = xf + ((size_t)b * L_ + l0 + w * 16 + l15) * C_ + g * 8;
#pragma unroll
  for (int ck = 0; ck < 8; ++ck) xfr[ck] = *(const f16x8*)(xr + ck * 32);
  __builtin_amdgcn_sched_barrier(0);
  if (DO_MU) {
#pragma unroll
    for (int q = 0; q < 8; ++q) {
      int s = q * 256 + t, c = s >> 3, sl = s & 7;
      gload16(xTf + (size_t)(b * C_ + c) * L_ + l0 + ((sl ^ (c & 7)) << 3), xtile + s * 8);
    }
    __builtin_amdgcn_sched_barrier(0);
    asm volatile("s_waitcnt vmcnt(8)" ::: "memory");
  } else {
    asm volatile("s_waitcnt vmcnt(0)" ::: "memory");
  }
  __builtin_amdgcn_s_barrier();
  __builtin_amdgcn_sched_barrier(0);

  f32x4 acc[4];
#pragma unroll
  for (int mt = 0; mt < 4; ++mt)
#pragma unroll
    for (int j = 0; j < 4; ++j) acc[mt][j] = 0.f;
#pragma unroll
  for (int ck = 0; ck < 8; ++ck) {
#pragma unroll
    for (int mt = 0; mt < 4; ++mt) {
      f16x8 a = *(const f16x8*)(mu_s + (mt * 16 + l15) * C_ + (((ck * 4 + g) ^ l15) << 3));
      acc[mt] = __builtin_amdgcn_mfma_f32_16x16x32_f16(a, xfr[ck], acc[mt], 0, 0, 0);
    }
  }

  float z[4][4];
  {
    float mx = acc[0][0];
#pragma unroll
    for (int mt = 0; mt < 4; ++mt)
#pragma unroll
      for (int jj = 0; jj < 4; ++jj) mx = fmaxf(mx, acc[mt][jj]);
    mx = fmaxf(mx, __shfl_xor(mx, 16, 64));
    mx = fmaxf(mx, __shfl_xor(mx, 32, 64));
    float sm = 0.f;
#pragma unroll
    for (int mt = 0; mt < 4; ++mt)
#pragma unroll
      for (int jj = 0; jj < 4; ++jj) {
        float e = __expf(acc[mt][jj] - mx);
        z[mt][jj] = e; sm += e;
      }
    sm += __shfl_xor(sm, 16, 64);
    sm += __shfl_xor(sm, 32, 64);
    float inv = 1.f / sm;
#pragma unroll
    for (int mt = 0; mt < 4; ++mt)
#pragma unroll
      for (int jj = 0; jj < 4; ++jj) z[mt][jj] *= inv;
  }

#pragma unroll
  for (int mt = 0; mt < 4; ++mt)
#pragma unroll
    for (int jj = 0; jj < 4; ++jj) {
      float v = z[mt][jj];
      v += __shfl_xor(v, 1, 64); v += __shfl_xor(v, 2, 64);
      v += __shfl_xor(v, 4, 64); v += __shfl_xor(v, 8, 64);
      if (l15 == 0) cpart[w][mt * 16 + g * 4 + jj] = v;
    }

#pragma unroll
  for (int mt = 0; mt < 4; ++mt)
#pragma unroll
    for (int jj = 0; jj < 4; ++jj) {
      int k = mt * 16 + g * 4 + jj;
      int tl = w * 16 + l15;
      f16 h = (f16)z[mt][jj];
      if (DO_MU)   zT_s[k * RPB + (((tl >> 3) ^ (k & 7)) << 3) + (tl & 7)] = h;
      if (WRITE_Z) zout[((size_t)b * L_ + l0 + tl) * K_ + k] = h;
    }
  __syncthreads();

  if (t < K_) {
    float s = 0.f;
#pragma unroll
    for (int q = 0; q < 4; ++q) s += cpart[q][t];
    cp[(size_t)chn * (B_ * K_) + b * K_ + t] = s;
  }

  if (DO_MU) {
    f32x4 a3[4][4];
#pragma unroll
    for (int mt = 0; mt < 4; ++mt)
#pragma unroll
      for (int nt = 0; nt < 4; ++nt)
#pragma unroll
        for (int j = 0; j < 4; ++j) a3[mt][nt][j] = 0.f;
    int cb = w * 64;
#pragma unroll
    for (int ks = 0; ks < 2; ++ks) {
      f16x8 az[4], bx[4];
#pragma unroll
      for (int mt = 0; mt < 4; ++mt)
        az[mt] = *(const f16x8*)(zT_s + (mt * 16 + l15) * RPB + (((ks * 4 + g) ^ (l15 & 7)) << 3));
#pragma unroll
      for (int nt = 0; nt < 4; ++nt) {
        int c = cb + nt * 16 + l15;
        bx[nt] = *(const f16x8*)(xtile + c * RPB + (((ks * 4 + g) ^ (c & 7)) << 3));
      }
#pragma unroll
      for (int mt = 0; mt < 4; ++mt)
#pragma unroll
        for (int nt = 0; nt < 4; ++nt)
          a3[mt][nt] = __builtin_amdgcn_mfma_f32_16x16x32_f16(az[mt], bx[nt], a3[mt][nt], 0, 0, 0);
    }
    f16* pp = part + (((size_t)chn * B_ + b) * K_) * C_;
#pragma unroll
    for (int mt = 0; mt < 4; ++mt)
#pragma unroll
      for (int nt = 0; nt < 4; ++nt)
#pragma unroll
        for (int jj = 0; jj < 4; ++jj)
          pp[(size_t)(mt * 16 + g * 4 + jj) * C_ + cb + nt * 16 + l15] = (f16)a3[mt][nt][jj];
  }
}

// ---------------------------------------------------------------- k_mufin
template<bool LAST>
__global__ __launch_bounds__(256) void k_mufin(
    const f16* __restrict__ part, const float* __restrict__ cp,
    f16* __restrict__ muF, f16* __restrict__ muT,
    float* __restrict__ zsA, float* __restrict__ outmu)
{
  int b = blockIdx.x >> 4, kg = blockIdx.x & 15, t = threadIdx.x;
  int kr = t >> 6, c4 = t & 63, k = kg * 4 + kr;
  float a0 = 0.f, a1 = 0.f, a2 = 0.f, a3 = 0.f;
#pragma unroll
  for (int chn = 0; chn < NCH; ++chn) {
    f16x4 p = *(const f16x4*)(part + (((size_t)chn * B_ + b) * K_ + k) * C_ + c4 * 4);
    a0 += (float)p[0]; a1 += (float)p[1]; a2 += (float)p[2]; a3 += (float)p[3];
  }
  float zs = 0.f;
#pragma unroll
  for (int chn = 0; chn < NCH; ++chn) zs += cp[(size_t)chn * (B_ * K_) + b * K_ + k];
  float sc = 1.f / (EPSF + zs);
  a0 *= sc; a1 *= sc; a2 *= sc; a3 *= sc;
  float ssq = a0 * a0 + a1 * a1 + a2 * a2 + a3 * a3;
#pragma unroll
  for (int off = 32; off >= 1; off >>= 1) ssq += __shfl_xor(ssq, off, 64);
  float inv = 1.f / (EPSF + sqrtf(ssq));
  a0 *= inv; a1 *= inv; a2 *= inv; a3 *= inv;
  size_t base = (size_t)(b * K_ + k) * C_ + c4 * 4;
  f16x4 hm; hm[0] = (f16)a0; hm[1] = (f16)a1; hm[2] = (f16)a2; hm[3] = (f16)a3;
  *(f16x4*)(muF + base) = hm;
  if (c4 == 0) zsA[b * K_ + k] = zs;
  if (LAST) {
    *(float4*)(outmu + base) = make_float4(a0, a1, a2, a3);
    muT[((size_t)b * C_ + c4 * 4 + 0) * K_ + k] = hm[0];
    muT[((size_t)b * C_ + c4 * 4 + 1) * K_ + k] = hm[1];
    muT[((size_t)b * C_ + c4 * 4 + 2) * K_ + k] = hm[2];
    muT[((size_t)b * C_ + c4 * 4 + 3) * K_ + k] = hm[3];
  }
}

// ---------------------------------------------------------------- k_attn
__global__ __launch_bounds__(256) void k_attn(
    const f16* __restrict__ zB, const float* __restrict__ cpB, float* __restrict__ attn)
{
  __shared__ float zt[64][68];
  __shared__ float inv_s[K_];
  int b = blockIdx.y, l0 = blockIdx.x * 64, t = threadIdx.x;
  if (t < K_) {
    float zs = 0.f;
#pragma unroll
    for (int chn = 0; chn < NCH; ++chn) zs += cpB[(size_t)chn * (B_ * K_) + b * K_ + t];
    inv_s[t] = 1.f / (EPSF + zs);
  }
  for (int p = 0; p < 16; ++p) {
    int e = t + p * 256, lo = e >> 6, k = e & 63;
    zt[lo][k] = (float)zB[((size_t)b * L_ + l0 + lo) * K_ + k];
  }
  __syncthreads();
  int lo = t & 63, kb = t >> 6;
  for (int p = 0; p < 16; ++p) {
    int k = kb * 16 + p;
    attn[((size_t)b * K_ + k) * L_ + l0 + lo] = zt[lo][k] * inv_s[k];
  }
}

// ---------------------------------------------------------------- k_mlp
// Design E: 8 waves (2/SIMD), 128 toks, pair (tt, ih) splits i/k range.
// sigma-permuted w1fr AND w2fr: recon D-regs -> GEMM1 B-frags -> GEMM2 B-frags
// entirely in registers. 1 barrier + 1 iter-old vmcnt(0) per iter.
constexpr int W1S_OFF  = 0;        // 2 x 32KB dbuf (prologue: muT 32KB + z 16KB)
constexpr int W2S_OFF  = 65536;    // 2 x 32KB dbuf
constexpr int BNS_OFF  = 131072;   // 8KB
constexpr int ZINV_OFF = 139264;   // 256B
constexpr int POOL_SZ  = 139520;

__global__ __launch_bounds__(512, 2) void k_mlp(
    const f16* __restrict__ zA,                  // [BL][64]
    const f16* __restrict__ muT,                 // [B][C][K]
    const float* __restrict__ zsA,               // [B][K]
    const unsigned short* __restrict__ w1fr,     // frag-ordered, bn-scaled, sigma
    const unsigned short* __restrict__ w2fr,     // frag-ordered, sigma
    const f16* __restrict__ bnshH, const float* __restrict__ b2,
    float* __restrict__ outr)                    // [BL][256] f32
{
  __shared__ __align__(16) char pool[POOL_SZ];
  unsigned short* w1s = (unsigned short*)(pool + W1S_OFF);
  unsigned short* w2s = (unsigned short*)(pool + W2S_OFF);
  f16* bns_s          = (f16*)(pool + BNS_OFF);
  float* zinv_s       = (float*)(pool + ZINV_OFF);
  f16* muT_s          = (f16*)(pool + 0);        // prologue overlay
  f16* z_s            = (f16*)(pool + 32768);    // prologue overlay

  int t = threadIdx.x, w = t >> 6, lane = t & 63, l31 = lane & 31, l5 = lane >> 5;
  int rb = blockIdx.x * 128, b = rb >> 11, l0 = rb & 2047;
  int tt = w & 3, ih = w >> 2;     // tok-tile, i/k-half

  // ---- prologue staging: zinv, muT (32KB), z (16KB), bns (8KB)
  if (t < K_) zinv_s[t] = 1.f / (EPSF + zsA[b * K_ + t]);
#pragma unroll
  for (int q = 0; q < 4; ++q) {
    int s = q * 512 + t, c = s >> 3, sl = s & 7;
    gload16(muT + ((size_t)b * C_ + c) * K_ + ((sl ^ (c & 7)) << 3), muT_s + s * 8);
  }
#pragma unroll
  for (int q = 0; q < 2; ++q) {
    int s = q * 512 + t, tok = s >> 3, sl = s & 7;
    gload16(zA + ((size_t)b * L_ + l0 + tok) * K_ + ((sl ^ (tok & 7)) << 3), z_s + s * 8);
  }
  gload16(bnshH + t * 8, bns_s + t * 8);
  asm volatile("s_waitcnt vmcnt(0) lgkmcnt(0)" ::: "memory");
  __builtin_amdgcn_s_barrier();
  __builtin_amdgcn_sched_barrier(0);

  // ---- recon MFMA (register-only): wave computes ALL 8 c-tiles for its 32 toks
  bf16x8 rc[16];
  {
    f16x8 bz[4];
#pragma unroll
    for (int kk = 0; kk < 4; ++kk) {
      int tok = tt * 32 + l31;
      f16x8 zr = *(const f16x8*)(z_s + tok * 64 + (((kk * 2 + l5) ^ (tok & 7)) << 3));
      f16x8 sc2;
#pragma unroll
      for (int e = 0; e < 8; ++e)
        sc2[e] = (f16)((float)zr[e] * zinv_s[kk * 16 + l5 * 8 + e]);
      bz[kk] = sc2;
    }
    f32x16 d[8];
#pragma unroll
    for (int m = 0; m < 8; ++m)
#pragma unroll
      for (int r = 0; r < 16; ++r) d[m][r] = 0.f;
#pragma unroll
    for (int kk = 0; kk < 4; ++kk) {
#pragma unroll
      for (int m = 0; m < 8; ++m) {
        int c = m * 32 + l31;
        f16x8 am = *(const f16x8*)(muT_s + c * 64 + (((kk * 2 + l5) ^ (c & 7)) << 3));
        d[m] = __builtin_amdgcn_mfma_f32_32x32x16_f16(am, bz[kk], d[m], 0, 0, 0);
      }
    }
    // D-regs -> B-frags: rc[2m + (r>>3)] element (r&7); pack even/odd pairs
    union Uf { unsigned u[4]; bf16x8 v; } rcU[16];
#pragma unroll
    for (int m = 0; m < 8; ++m)
#pragma unroll
      for (int q = 0; q < 8; ++q) {
        unsigned u = (unsigned)f2bf(d[m][2 * q]) | ((unsigned)f2bf(d[m][2 * q + 1]) << 16);
        rcU[2 * m + (q >> 2)].u[q & 3] = u;
      }
#pragma unroll
    for (int ks = 0; ks < 16; ++ks) rc[ks] = rcU[ks].v;
  }
  asm volatile("s_waitcnt lgkmcnt(0)" ::: "memory");
  __builtin_amdgcn_s_barrier();        // muT_s/z_s reads done -> pool reusable
  __builtin_amdgcn_sched_barrier(0);

  f32x16 acc2[8];
#pragma unroll
  for (int ot = 0; ot < 8; ++ot)
#pragma unroll
    for (int r = 0; r < 16; ++r) acc2[ot][r] = 0.f;

#define STAGE(ic, buf)                                                    \
  {                                                                       \
    _Pragma("unroll")                                                     \
    for (int q = 0; q < 4; ++q) {                                         \
      int d2 = q * 512 + t;                                               \
      gload16(w1fr + (size_t)(ic) * 16384 + d2 * 8,                       \
              w1s + (size_t)(buf) * 16384 + d2 * 8);                      \
    }                                                                     \
    _Pragma("unroll")                                                     \
    for (int q = 0; q < 4; ++q) {                                         \
      int d2 = q * 512 + t;                                               \
      gload16(w2fr + (size_t)(ic) * 16384 + d2 * 8,                       \
              w2s + (size_t)(buf) * 16384 + d2 * 8);                      \
    }                                                                     \
  }

  STAGE(0, 0);
  const unsigned short* p1base = w1s + ih * 8192 + l5 * 256 + l31 * 8;
  const unsigned short* p2base = w2s + ih * 8192 + l5 * 2048 + l31 * 8;

  for (int ic = 0; ic < 64; ++ic) {
    int cur = ic & 1;
    asm volatile("s_waitcnt vmcnt(0)" ::: "memory");   // STAGE(ic): iter-old
    __builtin_amdgcn_s_barrier();
    __builtin_amdgcn_sched_barrier(0);
    if (ic < 63) STAGE(ic + 1, cur ^ 1);
    __builtin_amdgcn_sched_barrier(0);

    // ---- GEMM1: h[i-half ih][wave's 32 toks], K=256 via rc[16]
    f32x16 h0, h1;
#pragma unroll
    for (int r = 0; r < 16; ++r) { h0[r] = 0.f; h1[r] = 0.f; }
    const unsigned short* p1 = p1base + cur * 16384;
#pragma unroll
    for (int ks = 0; ks < 16; ++ks) {
      bf16x8 a1 = *(const bf16x8*)(p1 + ks * 512);
      if (ks & 1) h1 = __builtin_amdgcn_mfma_f32_32x32x16_bf16(a1, rc[ks], h1, 0, 0, 0);
      else        h0 = __builtin_amdgcn_mfma_f32_32x32x16_bf16(a1, rc[ks], h0, 0, 0, 0);
    }
#pragma unroll
    for (int r = 0; r < 16; ++r) h0[r] += h1[r];

    // ---- BN shift + ReLU + pack into GEMM2 B-frags (registers only)
    f16x4 bnv[4];
#pragma unroll
    for (int q = 0; q < 4; ++q)
      bnv[q] = *(const f16x4*)(bns_s + ic * 64 + ih * 32 + 8 * q + 4 * l5);
    unsigned pk[8];
#pragma unroll
    for (int q = 0; q < 4; ++q) {
#pragma unroll
      for (int pr = 0; pr < 2; ++pr) {
        int r0 = q * 4 + pr * 2;
        float v0 = fmaxf(h0[r0]     + (float)bnv[q][pr * 2],     0.f);
        float v1 = fmaxf(h0[r0 + 1] + (float)bnv[q][pr * 2 + 1], 0.f);
        pk[q * 2 + pr] = (unsigned)f2bf(v0) | ((unsigned)f2bf(v1) << 16);
      }
    }
    union Uf { unsigned u[4]; bf16x8 v; };
    Uf bfr0, bfr1;
#pragma unroll
    for (int m = 0; m < 4; ++m) { bfr0.u[m] = pk[m]; bfr1.u[m] = pk[4 + m]; }

    // ---- GEMM2: 8 o-tiles, k-slices g = ic*4 + ih*2 + {0,1}
    const unsigned short* p2 = p2base + cur * 16384;
#pragma unroll
    for (int s = 0; s < 2; ++s) {
      bf16x8 bfv = s ? bfr1.v : bfr0.v;
#pragma unroll
      for (int ot = 0; ot < 8; ++ot) {
        bf16x8 a2 = *(const bf16x8*)(p2 + s * 4096 + ot * 256);
        acc2[ot] = __builtin_amdgcn_mfma_f32_32x32x16_bf16(a2, bfv, acc2[ot], 0, 0, 0);
      }
    }
  }
#undef STAGE

  // ---- pair reduction (ih=1 -> ih=0) via LDS, then epilogue store
  __syncthreads();                       // all LDS reads done; pool free
  float* red = (float*)pool;             // [tt4][ot8][r16][lane64] = 128KB
  if (ih == 1) {
#pragma unroll
    for (int ot = 0; ot < 8; ++ot)
#pragma unroll
      for (int r = 0; r < 16; ++r)
        red[((tt * 8 + ot) * 16 + r) * 64 + lane] = acc2[ot][r];
  }
  __syncthreads();
  if (ih == 0) {
    int tok = rb + tt * 32 + l31;
#pragma unroll
    for (int ot = 0; ot < 8; ++ot) {
#pragma unroll
      for (int r = 0; r < 16; ++r)
        acc2[ot][r] += red[((tt * 8 + ot) * 16 + r) * 64 + lane];
#pragma unroll
      for (int q = 0; q < 4; ++q) {
        int o = ot * 32 + 8 * q + 4 * l5;
        float4 bias = *(const float4*)(b2 + o);
        f32x4 v;
        v[0] = acc2[ot][q * 4 + 0] + bias.x;
        v[1] = acc2[ot][q * 4 + 1] + bias.y;
        v[2] = acc2[ot][q * 4 + 2] + bias.z;
        v[3] = acc2[ot][q * 4 + 3] + bias.w;
        *(f32x4*)(outr + (size_t)tok * C_ + o) = v;
      }
    }
  }
}

// ---------------------------------------------------------------- launch
extern "C" void kernel_launch(void* const* d_in, const int* in_sizes, int n_in,
                              void* d_out, int out_size, void* d_ws, size_t ws_size,
                              hipStream_t stream)
{
  const float* x     = (const float*)d_in[0];
  const float* mu0   = (const float*)d_in[2];
  const float* w1    = (const float*)d_in[3];
  const float* b1    = (const float*)d_in[4];
  const float* gamma = (const float*)d_in[5];
  const float* beta  = (const float*)d_in[6];
  const float* bmean = (const float*)d_in[7];
  const float* bvar  = (const float*)d_in[8];
  const float* w2    = (const float*)d_in[9];
  const float* b2    = (const float*)d_in[10];
  float* out = (float*)d_out;

  char* wsb = (char*)d_ws;
  f16* part = (f16*)(wsb + 0);                                  // 16,777,216 B
  f16* zB   = part;                                             // alias (dead after last mufin)
  f16* zA   = (f16*)(wsb + 16777216);                           // 4,194,304
  f16* xf   = (f16*)(wsb + 20971520);                           // 16,777,216
  f16* xTf  = (f16*)(wsb + 37748736);                           // 16,777,216
  unsigned short* w1fr = (unsigned short*)(wsb + 54525952);     // 2,097,152
  unsigned short* w2fr = (unsigned short*)(wsb + 56623104);     // 2,097,152
  f16*   muF   = (f16*)(wsb + 58720256);                        // 524,288
  f16*   muT   = (f16*)(wsb + 59244544);                        // 524,288
  f16*   bnshH = (f16*)(wsb + 59768832);                        // 8,192
  float* cpA   = (float*)(wsb + 59777024);                      // 131,072
  float* cpB   = (float*)(wsb + 59908096);                      // 131,072
  float* zsA   = (float*)(wsb + 60039168);                      // 4,096  (~60MB)

  k_pre<<<4096, 256, 0, stream>>>(w1, w2, gamma, beta, bmean, bvar, b1, mu0,
                                  w1fr, w2fr, bnshH, muF);
  k_xT<<<dim3(32, 4, 16), 256, 0, stream>>>(x, xf, xTf);

  for (int s = 0; s < 10; ++s) {
    if (s == 9) k_em<true, true ><<<dim3(NCH, 16), 256, 0, stream>>>(xf, xTf, muF, zA, cpA, part);
    else        k_em<true, false><<<dim3(NCH, 16), 256, 0, stream>>>(xf, xTf, muF, zA, cpA, part);
    if (s == 9) k_mufin<true ><<<256, 256, 0, stream>>>(part, cpA, muF, muT, zsA, out);
    else        k_mufin<false><<<256, 256, 0, stream>>>(part, cpA, muF, muT, zsA, out);
  }
  // new_z with final mu (no mu-update; zB overlays dead part buffer)
  k_em<false, true><<<dim3(NCH, 16), 256, 0, stream>>>(xf, xTf, muF, zB, cpB, part);
  k_attn<<<dim3(32, 16), 256, 0, stream>>>(zB, cpB, out + 262144);
  k_mlp<<<256, 512, 0, stream>>>(zA, muT, zsA, w1fr, w2fr, bnshH, b2, out + 2359296);
}

// Round 11
// 351.499 us; speedup vs baseline: 1.2193x; 1.0114x over previous
//
#include <hip/hip_runtime.h>

constexpr int B_ = 16, L_ = 2048, C_ = 256, K_ = 64, INNER_ = 4096;
constexpr int NCH = 32;          // L-chunks (RPB=64)
constexpr int RPB = 64;          // rows per k_em block
#define EPSF 1e-6f

typedef __attribute__((ext_vector_type(8)))  short bf16x8;
typedef __attribute__((ext_vector_type(4)))  float f32x4;
typedef __attribute__((ext_vector_type(16))) float f32x16;
typedef _Float16 f16;
typedef __attribute__((ext_vector_type(8))) _Float16 f16x8;
typedef __attribute__((ext_vector_type(4))) _Float16 f16x4;

__device__ __forceinline__ unsigned short f2bf(float f) {
  union { float f; unsigned u; } v; v.f = f;
  unsigned r = v.u + 0x7fffu + ((v.u >> 16) & 1u);   // RNE
  return (unsigned short)(r >> 16);
}

__device__ __forceinline__ void gload16(const void* src, void* lds) {
  __builtin_amdgcn_global_load_lds(
      (const __attribute__((address_space(1))) unsigned*)src,
      (__attribute__((address_space(3))) unsigned*)lds, 16, 0, 0);
}

// ---------------------------------------------------------------- k_pre
// w1fr: bn-scaled w1, GEMM1 A-frag order WITH sigma k-permutation:
//   f = ic*16384 + ih*8192 + ks*512 + l5*256 + l31*8 + j
//   holds w1[ic*64 + ih*32 + l31][ks*16 + 4*l5 + 8*(j>>2) + (j&3)] * bnscale
// w2fr: w2, GEMM2 A-frag order with same sigma:
//   f = g*4096 + l5*2048 + ot*256 + l31*8 + j
//   holds w2[ot*32 + l31][g*16 + 4*l5 + 8*(j>>2) + (j&3)]
__global__ __launch_bounds__(256) void k_pre(
    const float* __restrict__ w1, const float* __restrict__ w2,
    const float* __restrict__ gamma, const float* __restrict__ beta,
    const float* __restrict__ bmean, const float* __restrict__ bvar,
    const float* __restrict__ b1, const float* __restrict__ mu0,
    unsigned short* __restrict__ w1fr, unsigned short* __restrict__ w2fr,
    f16* __restrict__ bnshH, f16* __restrict__ muF)
{
  int i = blockIdx.x * 256 + threadIdx.x;     // covers 1048576
  if (i < INNER_ * C_) {
    int j = i & 7, l31 = (i >> 3) & 31;
    { // w1fr: l5 bit 8, ks bits 9-12, ih bit 13, ic bits 14+
      int l5 = (i >> 8) & 1, ks = (i >> 9) & 15, ih = (i >> 13) & 1, ic = i >> 14;
      int r1 = ic * 64 + ih * 32 + l31;             // 0..4095
      int c1 = ks * 16 + 4 * l5 + 8 * (j >> 2) + (j & 3);   // sigma
      float sc = gamma[r1] * rsqrtf(bvar[r1] + 1e-5f);
      w1fr[i] = f2bf(w1[(size_t)r1 * C_ + c1] * sc);
    }
    { // w2fr: ot bits 8-10, l5 bit 11, g bits 12+
      int ot = (i >> 8) & 7, l5 = (i >> 11) & 1, g = i >> 12;
      int o = ot * 32 + l31;
      int ii = g * 16 + 4 * l5 + 8 * (j >> 2) + (j & 3);
      w2fr[i] = f2bf(w2[(size_t)o * INNER_ + ii]);
    }
  }
  if (i < B_ * K_ * C_) muF[i] = (f16)mu0[i & (K_ * C_ - 1)];
  if (i < INNER_) {
    float sc = gamma[i] * rsqrtf(bvar[i] + 1e-5f);
    bnshH[i] = (f16)fmaf(b1[i] - bmean[i], sc, beta[i]);
  }
}

// ---------------------------------------------------------------- k_xT
__global__ __launch_bounds__(256) void k_xT(const float* __restrict__ x,
                                            f16* __restrict__ xf, f16* __restrict__ xTf)
{
  __shared__ float ts[64][65];
  int l0 = blockIdx.x * 64, c0 = blockIdx.y * 64, b = blockIdx.z;
  int t = threadIdx.x;
  for (int p = 0; p < 16; ++p) {
    int e = t + p * 256, i = e >> 6, j = e & 63;
    float vv = x[((size_t)b * L_ + l0 + i) * C_ + c0 + j];
    ts[i][j] = vv;
    xf[((size_t)b * L_ + l0 + i) * C_ + c0 + j] = (f16)vv;
  }
  __syncthreads();
  for (int p = 0; p < 16; ++p) {
    int e = t + p * 256, i = e >> 6, j = e & 63;
    xTf[((size_t)b * C_ + c0 + i) * L_ + l0 + j] = (f16)ts[j][i];
  }
}

// ---------------------------------------------------------------- k_em (r7, unchanged)
template<bool DO_MU, bool WRITE_Z>
__global__ __launch_bounds__(256, 2) void k_em(
    const f16* __restrict__ xf, const f16* __restrict__ xTf,
    const f16* __restrict__ muF, f16* __restrict__ zout,
    float* __restrict__ cp, f16* __restrict__ part)
{
  __shared__ f16 mu_s[K_ * C_];
  __shared__ f16 zT_s[K_ * RPB];
  __shared__ f16 xtile[C_ * RPB];
  __shared__ float cpart[4][K_];

  int t = threadIdx.x, b = blockIdx.y, chn = blockIdx.x, l0 = chn * RPB;
  int w = t >> 6, lane = t & 63, l15 = lane & 15, g = lane >> 4;

#pragma unroll
  for (int q = 0; q < 8; ++q) {
    int s = q * 256 + t, k = s >> 5, sl = s & 31;
    gload16(muF + (size_t)b * (K_ * C_) + k * C_ + ((sl ^ (k & 15)) << 3), mu_s + s * 8);
  }
  __builtin_amdgcn_sched_barrier(0);
  f16x8 xfr[8];
  const f16* xr = xf + ((size_t)b * L_ + l0 + w * 16 + l15) * C_ + g * 8;
#pragma unroll
  for (int ck = 0; ck < 8; ++ck) xfr[ck] = *(const f16x8*)(xr + ck * 32);
  __builtin_amdgcn_sched_barrier(0);
  if (DO_MU) {
#pragma unroll
    for (int q = 0; q < 8; ++q) {
      int s = q * 256 + t, c = s >> 3, sl = s & 7;
      gload16(xTf + (size_t)(b * C_ + c) * L_ + l0 + ((sl ^ (c & 7)) << 3), xtile + s * 8);
    }
    __builtin_amdgcn_sched_barrier(0);
    asm volatile("s_waitcnt vmcnt(8)" ::: "memory");
  } else {
    asm volatile("s_waitcnt vmcnt(0)" ::: "memory");
  }
  __builtin_amdgcn_s_barrier();
  __builtin_amdgcn_sched_barrier(0);

  f32x4 acc[4];
#pragma unroll
  for (int mt = 0; mt < 4; ++mt)
#pragma unroll
    for (int j = 0; j < 4; ++j) acc[mt][j] = 0.f;
#pragma unroll
  for (int ck = 0; ck < 8; ++ck) {
#pragma unroll
    for (int mt = 0; mt < 4; ++mt) {
      f16x8 a = *(const f16x8*)(mu_s + (mt * 16 + l15) * C_ + (((ck * 4 + g) ^ l15) << 3));
      acc[mt] = __builtin_amdgcn_mfma_f32_16x16x32_f16(a, xfr[ck], acc[mt], 0, 0, 0);
    }
  }

  float z[4][4];
  {
    float mx = acc[0][0];
#pragma unroll
    for (int mt = 0; mt < 4; ++mt)
#pragma unroll
      for (int jj = 0; jj < 4; ++jj) mx = fmaxf(mx, acc[mt][jj]);
    mx = fmaxf(mx, __shfl_xor(mx, 16, 64));
    mx = fmaxf(mx, __shfl_xor(mx, 32, 64));
    float sm = 0.f;
#pragma unroll
    for (int mt = 0; mt < 4; ++mt)
#pragma unroll
      for (int jj = 0; jj < 4; ++jj) {
        float e = __expf(acc[mt][jj] - mx);
        z[mt][jj] = e; sm += e;
      }
    sm += __shfl_xor(sm, 16, 64);
    sm += __shfl_xor(sm, 32, 64);
    float inv = 1.f / sm;
#pragma unroll
    for (int mt = 0; mt < 4; ++mt)
#pragma unroll
      for (int jj = 0; jj < 4; ++jj) z[mt][jj] *= inv;
  }

#pragma unroll
  for (int mt = 0; mt < 4; ++mt)
#pragma unroll
    for (int jj = 0; jj < 4; ++jj) {
      float v = z[mt][jj];
      v += __shfl_xor(v, 1, 64); v += __shfl_xor(v, 2, 64);
      v += __shfl_xor(v, 4, 64); v += __shfl_xor(v, 8, 64);
      if (l15 == 0) cpart[w][mt * 16 + g * 4 + jj] = v;
    }

#pragma unroll
  for (int mt = 0; mt < 4; ++mt)
#pragma unroll
    for (int jj = 0; jj < 4; ++jj) {
      int k = mt * 16 + g * 4 + jj;
      int tl = w * 16 + l15;
      f16 h = (f16)z[mt][jj];
      if (DO_MU)   zT_s[k * RPB + (((tl >> 3) ^ (k & 7)) << 3) + (tl & 7)] = h;
      if (WRITE_Z) zout[((size_t)b * L_ + l0 + tl) * K_ + k] = h;
    }
  __syncthreads();

  if (t < K_) {
    float s = 0.f;
#pragma unroll
    for (int q = 0; q < 4; ++q) s += cpart[q][t];
    cp[(size_t)chn * (B_ * K_) + b * K_ + t] = s;
  }

  if (DO_MU) {
    f32x4 a3[4][4];
#pragma unroll
    for (int mt = 0; mt < 4; ++mt)
#pragma unroll
      for (int nt = 0; nt < 4; ++nt)
#pragma unroll
        for (int j = 0; j < 4; ++j) a3[mt][nt][j] = 0.f;
    int cb = w * 64;
#pragma unroll
    for (int ks = 0; ks < 2; ++ks) {
      f16x8 az[4], bx[4];
#pragma unroll
      for (int mt = 0; mt < 4; ++mt)
        az[mt] = *(const f16x8*)(zT_s + (mt * 16 + l15) * RPB + (((ks * 4 + g) ^ (l15 & 7)) << 3));
#pragma unroll
      for (int nt = 0; nt < 4; ++nt) {
        int c = cb + nt * 16 + l15;
        bx[nt] = *(const f16x8*)(xtile + c * RPB + (((ks * 4 + g) ^ (c & 7)) << 3));
      }
#pragma unroll
      for (int mt = 0; mt < 4; ++mt)
#pragma unroll
        for (int nt = 0; nt < 4; ++nt)
          a3[mt][nt] = __builtin_amdgcn_mfma_f32_16x16x32_f16(az[mt], bx[nt], a3[mt][nt], 0, 0, 0);
    }
    f16* pp = part + (((size_t)chn * B_ + b) * K_) * C_;
#pragma unroll
    for (int mt = 0; mt < 4; ++mt)
#pragma unroll
      for (int nt = 0; nt < 4; ++nt)
#pragma unroll
        for (int jj = 0; jj < 4; ++jj)
          pp[(size_t)(mt * 16 + g * 4 + jj) * C_ + cb + nt * 16 + l15] = (f16)a3[mt][nt][jj];
  }
}

// ---------------------------------------------------------------- k_mufin
template<bool LAST>
__global__ __launch_bounds__(256) void k_mufin(
    const f16* __restrict__ part, const float* __restrict__ cp,
    f16* __restrict__ muF, f16* __restrict__ muT,
    float* __restrict__ zsA, float* __restrict__ outmu)
{
  int b = blockIdx.x >> 4, kg = blockIdx.x & 15, t = threadIdx.x;
  int kr = t >> 6, c4 = t & 63, k = kg * 4 + kr;
  float a0 = 0.f, a1 = 0.f, a2 = 0.f, a3 = 0.f;
#pragma unroll
  for (int chn = 0; chn < NCH; ++chn) {
    f16x4 p = *(const f16x4*)(part + (((size_t)chn * B_ + b) * K_ + k) * C_ + c4 * 4);
    a0 += (float)p[0]; a1 += (float)p[1]; a2 += (float)p[2]; a3 += (float)p[3];
  }
  float zs = 0.f;
#pragma unroll
  for (int chn = 0; chn < NCH; ++chn) zs += cp[(size_t)chn * (B_ * K_) + b * K_ + k];
  float sc = 1.f / (EPSF + zs);
  a0 *= sc; a1 *= sc; a2 *= sc; a3 *= sc;
  float ssq = a0 * a0 + a1 * a1 + a2 * a2 + a3 * a3;
#pragma unroll
  for (int off = 32; off >= 1; off >>= 1) ssq += __shfl_xor(ssq, off, 64);
  float inv = 1.f / (EPSF + sqrtf(ssq));
  a0 *= inv; a1 *= inv; a2 *= inv; a3 *= inv;
  size_t base = (size_t)(b * K_ + k) * C_ + c4 * 4;
  f16x4 hm; hm[0] = (f16)a0; hm[1] = (f16)a1; hm[2] = (f16)a2; hm[3] = (f16)a3;
  *(f16x4*)(muF + base) = hm;
  if (c4 == 0) zsA[b * K_ + k] = zs;
  if (LAST) {
    *(float4*)(outmu + base) = make_float4(a0, a1, a2, a3);
    muT[((size_t)b * C_ + c4 * 4 + 0) * K_ + k] = hm[0];
    muT[((size_t)b * C_ + c4 * 4 + 1) * K_ + k] = hm[1];
    muT[((size_t)b * C_ + c4 * 4 + 2) * K_ + k] = hm[2];
    muT[((size_t)b * C_ + c4 * 4 + 3) * K_ + k] = hm[3];
  }
}

// ---------------------------------------------------------------- k_attn
__global__ __launch_bounds__(256) void k_attn(
    const f16* __restrict__ zB, const float* __restrict__ cpB, float* __restrict__ attn)
{
  __shared__ float zt[64][68];
  __shared__ float inv_s[K_];
  int b = blockIdx.y, l0 = blockIdx.x * 64, t = threadIdx.x;
  if (t < K_) {
    float zs = 0.f;
#pragma unroll
    for (int chn = 0; chn < NCH; ++chn) zs += cpB[(size_t)chn * (B_ * K_) + b * K_ + t];
    inv_s[t] = 1.f / (EPSF + zs);
  }
  for (int p = 0; p < 16; ++p) {
    int e = t + p * 256, lo = e >> 6, k = e & 63;
    zt[lo][k] = (float)zB[((size_t)b * L_ + l0 + lo) * K_ + k];
  }
  __syncthreads();
  int lo = t & 63, kb = t >> 6;
  for (int p = 0; p < 16; ++p) {
    int k = kb * 16 + p;
    attn[((size_t)b * K_ + k) * L_ + l0 + lo] = zt[lo][k] * inv_s[k];
  }
}

// ---------------------------------------------------------------- k_mlp
// Design E + T5 setprio + overlapped prologue:
// 8 waves (2/SIMD), 128 toks, pair (tt, ih) splits i/k range. sigma-permuted
// w1fr/w2fr keep the whole recon->GEMM1->GEMM2 handoff in registers.
// Prologue overlays live in the buf1 halves so STAGE(0)->buf0 flies under recon.
constexpr int W1S_OFF  = 0;        // 2 x 32KB dbuf
constexpr int W2S_OFF  = 65536;    // 2 x 32KB dbuf
constexpr int BNS_OFF  = 131072;   // 8KB
constexpr int ZINV_OFF = 139264;   // 256B
constexpr int POOL_SZ  = 139520;

__global__ __launch_bounds__(512, 2) void k_mlp(
    const f16* __restrict__ zA,                  // [BL][64]
    const f16* __restrict__ muT,                 // [B][C][K]
    const float* __restrict__ zsA,               // [B][K]
    const unsigned short* __restrict__ w1fr,     // frag-ordered, bn-scaled, sigma
    const unsigned short* __restrict__ w2fr,     // frag-ordered, sigma
    const f16* __restrict__ bnshH, const float* __restrict__ b2,
    float* __restrict__ outr)                    // [BL][256] f32
{
  __shared__ __align__(16) char pool[POOL_SZ];
  unsigned short* w1s = (unsigned short*)(pool + W1S_OFF);
  unsigned short* w2s = (unsigned short*)(pool + W2S_OFF);
  f16* bns_s          = (f16*)(pool + BNS_OFF);
  float* zinv_s       = (float*)(pool + ZINV_OFF);
  f16* muT_s          = (f16*)(pool + W1S_OFF + 32768);   // buf1 overlay (32KB)
  f16* z_s            = (f16*)(pool + W2S_OFF + 32768);   // buf1 overlay (16KB)

  int t = threadIdx.x, w = t >> 6, lane = t & 63, l31 = lane & 31, l5 = lane >> 5;
  int rb = blockIdx.x * 128, b = rb >> 11, l0 = rb & 2047;
  int tt = w & 3, ih = w >> 2;     // tok-tile, i/k-half

#define STAGE(ic, buf)                                                    \
  {                                                                       \
    _Pragma("unroll")                                                     \
    for (int q = 0; q < 4; ++q) {                                         \
      int d2 = q * 512 + t;                                               \
      gload16(w1fr + (size_t)(ic) * 16384 + d2 * 8,                       \
              w1s + (size_t)(buf) * 16384 + d2 * 8);                      \
    }                                                                     \
    _Pragma("unroll")                                                     \
    for (int q = 0; q < 4; ++q) {                                         \
      int d2 = q * 512 + t;                                               \
      gload16(w2fr + (size_t)(ic) * 16384 + d2 * 8,                       \
              w2s + (size_t)(buf) * 16384 + d2 * 8);                      \
    }                                                                     \
  }

  // ---- prologue: zinv first (its wait covers only zsA), then 7 DMAs,
  //      then STAGE(0)->buf0 (stays in flight under recon: vmcnt(8)).
  if (t < K_) zinv_s[t] = 1.f / (EPSF + zsA[b * K_ + t]);
  __builtin_amdgcn_sched_barrier(0);
#pragma unroll
  for (int q = 0; q < 4; ++q) {
    int s = q * 512 + t, c = s >> 3, sl = s & 7;
    gload16(muT + ((size_t)b * C_ + c) * K_ + ((sl ^ (c & 7)) << 3), muT_s + s * 8);
  }
#pragma unroll
  for (int q = 0; q < 2; ++q) {
    int s = q * 512 + t, tok = s >> 3, sl = s & 7;
    gload16(zA + ((size_t)b * L_ + l0 + tok) * K_ + ((sl ^ (tok & 7)) << 3), z_s + s * 8);
  }
  gload16(bnshH + t * 8, bns_s + t * 8);
  __builtin_amdgcn_sched_barrier(0);
  STAGE(0, 0);
  __builtin_amdgcn_sched_barrier(0);
  asm volatile("s_waitcnt vmcnt(8) lgkmcnt(0)" ::: "memory");   // prologue landed
  __builtin_amdgcn_s_barrier();
  __builtin_amdgcn_sched_barrier(0);

  // ---- recon MFMA (register-only): wave computes ALL 8 c-tiles for its 32 toks
  bf16x8 rc[16];
  {
    f16x8 bz[4];
#pragma unroll
    for (int kk = 0; kk < 4; ++kk) {
      int tok = tt * 32 + l31;
      f16x8 zr = *(const f16x8*)(z_s + tok * 64 + (((kk * 2 + l5) ^ (tok & 7)) << 3));
      f16x8 sc2;
#pragma unroll
      for (int e = 0; e < 8; ++e)
        sc2[e] = (f16)((float)zr[e] * zinv_s[kk * 16 + l5 * 8 + e]);
      bz[kk] = sc2;
    }
    f32x16 d[8];
#pragma unroll
    for (int m = 0; m < 8; ++m)
#pragma unroll
      for (int r = 0; r < 16; ++r) d[m][r] = 0.f;
#pragma unroll
    for (int kk = 0; kk < 4; ++kk) {
#pragma unroll
      for (int m = 0; m < 8; ++m) {
        int c = m * 32 + l31;
        f16x8 am = *(const f16x8*)(muT_s + c * 64 + (((kk * 2 + l5) ^ (c & 7)) << 3));
        d[m] = __builtin_amdgcn_mfma_f32_32x32x16_f16(am, bz[kk], d[m], 0, 0, 0);
      }
    }
    // D-regs -> B-frags: rc[2m + (r>>3)] element (r&7); pack even/odd pairs
    union Uf { unsigned u[4]; bf16x8 v; } rcU[16];
#pragma unroll
    for (int m = 0; m < 8; ++m)
#pragma unroll
      for (int q = 0; q < 8; ++q) {
        unsigned u = (unsigned)f2bf(d[m][2 * q]) | ((unsigned)f2bf(d[m][2 * q + 1]) << 16);
        rcU[2 * m + (q >> 2)].u[q & 3] = u;
      }
#pragma unroll
    for (int ks = 0; ks < 16; ++ks) rc[ks] = rcU[ks].v;
  }
  asm volatile("s_waitcnt lgkmcnt(0)" ::: "memory");
  __builtin_amdgcn_s_barrier();        // muT_s/z_s reads done -> buf1 reusable
  __builtin_amdgcn_sched_barrier(0);

  f32x16 acc2[8];
#pragma unroll
  for (int ot = 0; ot < 8; ++ot)
#pragma unroll
    for (int r = 0; r < 16; ++r) acc2[ot][r] = 0.f;

  const unsigned short* p1base = w1s + ih * 8192 + l5 * 256 + l31 * 8;
  const unsigned short* p2base = w2s + ih * 8192 + l5 * 2048 + l31 * 8;

  for (int ic = 0; ic < 64; ++ic) {
    int cur = ic & 1;
    asm volatile("s_waitcnt vmcnt(0)" ::: "memory");   // STAGE(ic): iter-old
    __builtin_amdgcn_s_barrier();
    __builtin_amdgcn_sched_barrier(0);
    if (ic < 63) STAGE(ic + 1, cur ^ 1);
    __builtin_amdgcn_sched_barrier(0);

    // ---- GEMM1: h[i-half ih][wave's 32 toks], K=256 via rc[16]
    f32x16 h0, h1;
#pragma unroll
    for (int r = 0; r < 16; ++r) { h0[r] = 0.f; h1[r] = 0.f; }
    const unsigned short* p1 = p1base + cur * 16384;
    __builtin_amdgcn_s_setprio(1);
#pragma unroll
    for (int ks = 0; ks < 16; ++ks) {
      bf16x8 a1 = *(const bf16x8*)(p1 + ks * 512);
      if (ks & 1) h1 = __builtin_amdgcn_mfma_f32_32x32x16_bf16(a1, rc[ks], h1, 0, 0, 0);
      else        h0 = __builtin_amdgcn_mfma_f32_32x32x16_bf16(a1, rc[ks], h0, 0, 0, 0);
    }
    __builtin_amdgcn_s_setprio(0);
#pragma unroll
    for (int r = 0; r < 16; ++r) h0[r] += h1[r];

    // ---- BN shift + ReLU + pack into GEMM2 B-frags (registers only)
    f16x4 bnv[4];
#pragma unroll
    for (int q = 0; q < 4; ++q)
      bnv[q] = *(const f16x4*)(bns_s + ic * 64 + ih * 32 + 8 * q + 4 * l5);
    unsigned pk[8];
#pragma unroll
    for (int q = 0; q < 4; ++q) {
#pragma unroll
      for (int pr = 0; pr < 2; ++pr) {
        int r0 = q * 4 + pr * 2;
        float v0 = fmaxf(h0[r0]     + (float)bnv[q][pr * 2],     0.f);
        float v1 = fmaxf(h0[r0 + 1] + (float)bnv[q][pr * 2 + 1], 0.f);
        pk[q * 2 + pr] = (unsigned)f2bf(v0) | ((unsigned)f2bf(v1) << 16);
      }
    }
    union Uf { unsigned u[4]; bf16x8 v; };
    Uf bfr0, bfr1;
#pragma unroll
    for (int m = 0; m < 4; ++m) { bfr0.u[m] = pk[m]; bfr1.u[m] = pk[4 + m]; }

    // ---- GEMM2: 8 o-tiles, k-slices g = ic*4 + ih*2 + {0,1}
    const unsigned short* p2 = p2base + cur * 16384;
    __builtin_amdgcn_s_setprio(1);
#pragma unroll
    for (int s = 0; s < 2; ++s) {
      bf16x8 bfv = s ? bfr1.v : bfr0.v;
#pragma unroll
      for (int ot = 0; ot < 8; ++ot) {
        bf16x8 a2 = *(const bf16x8*)(p2 + s * 4096 + ot * 256);
        acc2[ot] = __builtin_amdgcn_mfma_f32_32x32x16_bf16(a2, bfv, acc2[ot], 0, 0, 0);
      }
    }
    __builtin_amdgcn_s_setprio(0);
  }
#undef STAGE

  // ---- pair reduction (ih=1 -> ih=0) via LDS, then epilogue store
  __syncthreads();                       // all LDS reads done; pool free
  float* red = (float*)pool;             // [tt4][ot8][r16][lane64] = 128KB
  if (ih == 1) {
#pragma unroll
    for (int ot = 0; ot < 8; ++ot)
#pragma unroll
      for (int r = 0; r < 16; ++r)
        red[((tt * 8 + ot) * 16 + r) * 64 + lane] = acc2[ot][r];
  }
  __syncthreads();
  if (ih == 0) {
    int tok = rb + tt * 32 + l31;
#pragma unroll
    for (int ot = 0; ot < 8; ++ot) {
#pragma unroll
      for (int r = 0; r < 16; ++r)
        acc2[ot][r] += red[((tt * 8 + ot) * 16 + r) * 64 + lane];
#pragma unroll
      for (int q = 0; q < 4; ++q) {
        int o = ot * 32 + 8 * q + 4 * l5;
        float4 bias = *(const float4*)(b2 + o);
        f32x4 v;
        v[0] = acc2[ot][q * 4 + 0] + bias.x;
        v[1] = acc2[ot][q * 4 + 1] + bias.y;
        v[2] = acc2[ot][q * 4 + 2] + bias.z;
        v[3] = acc2[ot][q * 4 + 3] + bias.w;
        *(f32x4*)(outr + (size_t)tok * C_ + o) = v;
      }
    }
  }
}

// ---------------------------------------------------------------- launch
extern "C" void kernel_launch(void* const* d_in, const int* in_sizes, int n_in,
                              void* d_out, int out_size, void* d_ws, size_t ws_size,
                              hipStream_t stream)
{
  const float* x     = (const float*)d_in[0];
  const float* mu0   = (const float*)d_in[2];
  const float* w1    = (const float*)d_in[3];
  const float* b1    = (const float*)d_in[4];
  const float* gamma = (const float*)d_in[5];
  const float* beta  = (const float*)d_in[6];
  const float* bmean = (const float*)d_in[7];
  const float* bvar  = (const float*)d_in[8];
  const float* w2    = (const float*)d_in[9];
  const float* b2    = (const float*)d_in[10];
  float* out = (float*)d_out;

  char* wsb = (char*)d_ws;
  f16* part = (f16*)(wsb + 0);                                  // 16,777,216 B
  f16* zB   = part;                                             // alias (dead after last mufin)
  f16* zA   = (f16*)(wsb + 16777216);                           // 4,194,304
  f16* xf   = (f16*)(wsb + 20971520);                           // 16,777,216
  f16* xTf  = (f16*)(wsb + 37748736);                           // 16,777,216
  unsigned short* w1fr = (unsigned short*)(wsb + 54525952);     // 2,097,152
  unsigned short* w2fr = (unsigned short*)(wsb + 56623104);     // 2,097,152
  f16*   muF   = (f16*)(wsb + 58720256);                        // 524,288
  f16*   muT   = (f16*)(wsb + 59244544);                        // 524,288
  f16*   bnshH = (f16*)(wsb + 59768832);                        // 8,192
  float* cpA   = (float*)(wsb + 59777024);                      // 131,072
  float* cpB   = (float*)(wsb + 59908096);                      // 131,072
  float* zsA   = (float*)(wsb + 60039168);                      // 4,096  (~60MB)

  k_pre<<<4096, 256, 0, stream>>>(w1, w2, gamma, beta, bmean, bvar, b1, mu0,
                                  w1fr, w2fr, bnshH, muF);
  k_xT<<<dim3(32, 4, 16), 256, 0, stream>>>(x, xf, xTf);

  for (int s = 0; s < 10; ++s) {
    if (s == 9) k_em<true, true ><<<dim3(NCH, 16), 256, 0, stream>>>(xf, xTf, muF, zA, cpA, part);
    else        k_em<true, false><<<dim3(NCH, 16), 256, 0, stream>>>(xf, xTf, muF, zA, cpA, part);
    if (s == 9) k_mufin<true ><<<256, 256, 0, stream>>>(part, cpA, muF, muT, zsA, out);
    else        k_mufin<false><<<256, 256, 0, stream>>>(part, cpA, muF, muT, zsA, out);
  }
  // new_z with final mu (no mu-update; zB overlays dead part buffer)
  k_em<false, true><<<dim3(NCH, 16), 256, 0, stream>>>(xf, xTf, muF, zB, cpB, part);
  k_attn<<<dim3(32, 16), 256, 0, stream>>>(zB, cpB, out + 262144);
  k_mlp<<<256, 512, 0, stream>>>(zA, muT, zsA, w1fr, w2fr, bnshH, b2, out + 2359296);
}